// Round 5
// baseline (117.745 us; speedup 1.0000x reference)
//
#include <hip/hip_runtime.h>

#define NSEQ 2048
#define DH 64
#define NH 16
#define BKV 64
#define PSTRIDE 8448  // 128*64 acc + 128 m + 128 l floats per partial

typedef __attribute__((ext_vector_type(8))) short bf16x8;
typedef __attribute__((ext_vector_type(4))) short s16x4;
typedef __attribute__((ext_vector_type(4))) float f32x4;
typedef __attribute__((ext_vector_type(16))) float f32x16;
typedef __attribute__((ext_vector_type(4))) unsigned u32x4;

static __device__ __forceinline__ short f2bf(float f) {
    __bf16 b = (__bf16)f;              // HW cvt (RNE); pairs fuse to v_cvt_pk_bf16_f32
    return __builtin_bit_cast(short, b);
}

// ---------------- gating ----------------
__global__ void gate_partial(const float* __restrict__ gi, float* __restrict__ wsA, int SL) {
    int b = blockIdx.x / SL, sl = blockIdx.x % SL;
    int rows = NSEQ / SL;
    int tid = threadIdx.x;
    int g = tid & 127, half = tid >> 7;
    float s = 0.f;
    int n0 = sl * rows;
    for (int n = n0 + half; n < n0 + rows; n += 2)
        s += gi[((size_t)b * NSEQ + n) * 128 + g];
    __shared__ float part[2][128];
    part[half][g] = s;
    __syncthreads();
    if (tid < 128) wsA[(b * SL + sl) * 128 + tid] = part[0][tid] + part[1][tid];
}

__global__ void gate_final(const float* __restrict__ wsA, const float* __restrict__ Wg,
                           const float* __restrict__ bg, float* __restrict__ ws_sm,
                           int* __restrict__ ws_idx, int SL) {
    int b = blockIdx.x, tid = threadIdx.x;
    __shared__ float meanv[128];
    __shared__ float logits[NH];
    if (tid < 128) {
        float s = 0.f;
        for (int sl = 0; sl < SL; ++sl) s += wsA[(b * SL + sl) * 128 + tid];
        meanv[tid] = s * (1.0f / NSEQ);
    }
    __syncthreads();
    if (tid < 128) {
        int h = tid >> 3, j = tid & 7;
        float p = 0.f;
        for (int i = 0; i < 16; ++i) { int g = j + 8 * i; p += meanv[g] * Wg[h * 128 + g]; }
        p += __shfl_xor(p, 1);
        p += __shfl_xor(p, 2);
        p += __shfl_xor(p, 4);
        if (j == 0) logits[h] = p + bg[h];
    }
    __syncthreads();
    if (tid == 0) {
        float mx = logits[0];
        for (int h = 1; h < NH; ++h) mx = fmaxf(mx, logits[h]);
        float e[NH], sum = 0.f;
        for (int h = 0; h < NH; ++h) { e[h] = __expf(logits[h] - mx); sum += e[h]; }
        float inv = 1.0f / sum;
        for (int h = 0; h < NH; ++h) ws_sm[b * NH + h] = e[h] * inv;
        int i1 = 0;
        for (int h = 1; h < NH; ++h) if (logits[h] > logits[i1]) i1 = h;
        int i2 = (i1 == 0) ? 1 : 0;
        for (int h = 0; h < NH; ++h) if (h != i1 && logits[h] > logits[i2]) i2 = h;
        ws_idx[b * 2 + 0] = i1;
        ws_idx[b * 2 + 1] = i2;
    }
}

static __device__ __forceinline__ void lb_compute(const float* ws_sm, const int* ws_idx,
                                                  float* out_lb) {
    float counts[NH];
    for (int h = 0; h < NH; ++h) counts[h] = 0.f;
    for (int i = 0; i < 16; ++i) counts[ws_idx[i]] += 1.0f;
    float lb = 0.f;
    for (int h = 0; h < NH; ++h) {
        float msm = 0.f;
        for (int b = 0; b < 8; ++b) msm += ws_sm[b * NH + h];
        msm *= (1.0f / 8.0f);
        lb += msm * (counts[h] / (16.0f + 1e-6f));
    }
    out_lb[0] = lb * (float)NH;
}

__global__ void lb_kernel(const float* __restrict__ ws_sm, const int* __restrict__ ws_idx,
                          float* __restrict__ out_lb) {
    if (threadIdx.x == 0 && blockIdx.x == 0) lb_compute(ws_sm, ws_idx, out_lb);
}

// ---------------- attention: 32x32 swapped-QK^T flash, KV-split ----------------
template<int SPLIT>
__global__ __launch_bounds__(256, 3)
void attn_kernel(const float* __restrict__ q, const float* __restrict__ k,
                 const float* __restrict__ v, const float* __restrict__ mask,
                 const int* __restrict__ topk, float* __restrict__ out,
                 float* __restrict__ part) {
    const int qt = blockIdx.x & 15;   // q-tile (128 rows each)
    const int sp = blockIdx.x >> 4;   // kv split
    const int kk = blockIdx.y;
    const int b  = blockIdx.z;
    const int hh = topk[b * 2 + kk];
    const int tid = threadIdx.x;
    const int wave = tid >> 6;
    const int lane = tid & 63;
    const int lq = lane & 31;         // q-col (S^T) / d-col (O) / kv-row (K-frag)
    const int hi = lane >> 5;         // half selector

    const int nt = 32 / SPLIT;
    const int t_begin = sp * nt;

    __shared__ short Kb[64][72];      // [kv][d]  9216 B
    __shared__ short Vt[64][72];      // [d][kv]  9216 B
    __shared__ float scb[4][32];      // per-wave rescale broadcast

    const float QSC = 0.125f * 1.4426950408889634f;
    const float MSC = 1.4426950408889634f;
    const float THR = 10.0f;          // defer-max threshold (log2 units)

    const size_t headoff = ((size_t)b * NH + hh) * (size_t)NSEQ * DH;
    const int qbase = qt * 128 + wave * 32;

    // Q fragments (B-operand): lane: q-col = qbase+lq, k-slot j -> d = dk*16 + hi*8 + j
    bf16x8 qf[4];
    {
        const float* qp = q + headoff + (size_t)(qbase + lq) * DH;
        #pragma unroll
        for (int dk = 0; dk < 4; ++dk) {
            const float* p = qp + dk * 16 + hi * 8;
            float4 a = *(const float4*)p;
            float4 c = *(const float4*)(p + 4);
            bf16x8 f = { f2bf(a.x * QSC), f2bf(a.y * QSC), f2bf(a.z * QSC), f2bf(a.w * QSC),
                         f2bf(c.x * QSC), f2bf(c.y * QSC), f2bf(c.z * QSC), f2bf(c.w * QSC) };
            qf[dk] = f;
        }
    }

    f32x16 acc0, acc1;
    #pragma unroll
    for (int r = 0; r < 16; ++r) { acc0[r] = 0.f; acc1[r] = 0.f; }
    float m_r = -1e30f, l_r = 0.f;

    const float* kb = k + headoff;
    const float* vb = v + headoff;
    const float* mb = mask + (size_t)b * NSEQ * NSEQ + (size_t)(qbase + lq) * NSEQ;

    const int krow = tid >> 3;          // 0..31
    const int kcol = (tid & 7) * 8;     // 0..56
    const int vrow = (tid & 15) * 4;    // kv 0..60
    const int vcol = (tid >> 4) * 4;    // d  0..60

    float4 kreg[4], vreg[4], mreg[8];

    auto issue_kv = [&](int t0) {
        const float* kp = kb + (size_t)(t0 + krow) * DH + kcol;
        kreg[0] = *(const float4*)kp;
        kreg[1] = *(const float4*)(kp + 4);
        kreg[2] = *(const float4*)(kp + 32 * DH);
        kreg[3] = *(const float4*)(kp + 32 * DH + 4);
        const float* vp = vb + (size_t)(t0 + vrow) * DH + vcol;
        #pragma unroll
        for (int i = 0; i < 4; ++i) vreg[i] = *(const float4*)(vp + i * DH);
    };
    auto issue_mask = [&](int t0) {
        const float* mp = mb + t0 + hi * 4;
        #pragma unroll
        for (int g = 0; g < 4; ++g) {
            mreg[g]     = *(const float4*)(mp + g * 8);
            mreg[4 + g] = *(const float4*)(mp + 32 + g * 8);
        }
    };

    auto pack2 = [&](float a, float bb) -> unsigned {
        union { short s[2]; unsigned u; } t;
        t.s[0] = f2bf(a); t.s[1] = f2bf(bb);
        return t.u;
    };
    // build PV A-frag for one 16-kv chunk from 8 in-lane P values
    auto buildfrag = [&](float a0, float a1, float a2, float a3,
                         float a4, float a5, float a6, float a7) -> bf16x8 {
        unsigned pk01 = pack2(a0, a1), pk23 = pack2(a2, a3);
        unsigned pk45 = pack2(a4, a5), pk67 = pack2(a6, a7);
        unsigned ta = hi ? pk01 : pk45;
        unsigned tb = hi ? pk23 : pk67;
        unsigned ya = __shfl_xor(ta, 32);
        unsigned yb = __shfl_xor(tb, 32);
        u32x4 fr = { hi ? ya : pk01, hi ? yb : pk23,
                     hi ? pk45 : ya, hi ? pk67 : yb };
        return __builtin_bit_cast(bf16x8, fr);
    };

    issue_kv(t_begin * BKV);
    issue_mask(t_begin * BKV);

    for (int t = 0; t < nt; ++t) {
        const int t0 = (t_begin + t) * BKV;
        __syncthreads();
        // ---- stage K (2 x b128) and V^T (4 x b64) ----
        {
            bf16x8 k0 = { f2bf(kreg[0].x), f2bf(kreg[0].y), f2bf(kreg[0].z), f2bf(kreg[0].w),
                          f2bf(kreg[1].x), f2bf(kreg[1].y), f2bf(kreg[1].z), f2bf(kreg[1].w) };
            bf16x8 k1 = { f2bf(kreg[2].x), f2bf(kreg[2].y), f2bf(kreg[2].z), f2bf(kreg[2].w),
                          f2bf(kreg[3].x), f2bf(kreg[3].y), f2bf(kreg[3].z), f2bf(kreg[3].w) };
            *(bf16x8*)&Kb[krow][kcol] = k0;
            *(bf16x8*)&Kb[krow + 32][kcol] = k1;
            s16x4 c0v = { f2bf(vreg[0].x), f2bf(vreg[1].x), f2bf(vreg[2].x), f2bf(vreg[3].x) };
            s16x4 c1v = { f2bf(vreg[0].y), f2bf(vreg[1].y), f2bf(vreg[2].y), f2bf(vreg[3].y) };
            s16x4 c2v = { f2bf(vreg[0].z), f2bf(vreg[1].z), f2bf(vreg[2].z), f2bf(vreg[3].z) };
            s16x4 c3v = { f2bf(vreg[0].w), f2bf(vreg[1].w), f2bf(vreg[2].w), f2bf(vreg[3].w) };
            *(s16x4*)&Vt[vcol + 0][vrow] = c0v;
            *(s16x4*)&Vt[vcol + 1][vrow] = c1v;
            *(s16x4*)&Vt[vcol + 2][vrow] = c2v;
            *(s16x4*)&Vt[vcol + 3][vrow] = c3v;
        }
        __syncthreads();

        // ---- S^T = K . Q^T : lane holds one q-row (col=lq), kv rows per C/D map ----
        f32x16 S0, S1;
        #pragma unroll
        for (int r = 0; r < 16; ++r) { S0[r] = 0.f; S1[r] = 0.f; }
        #pragma unroll
        for (int dk = 0; dk < 4; ++dk) {
            bf16x8 kf0 = *(const bf16x8*)&Kb[lq][dk * 16 + hi * 8];
            bf16x8 kf1 = *(const bf16x8*)&Kb[32 + lq][dk * 16 + hi * 8];
            S0 = __builtin_amdgcn_mfma_f32_32x32x16_bf16(kf0, qf[dk], S0, 0, 0, 0);
            S1 = __builtin_amdgcn_mfma_f32_32x32x16_bf16(kf1, qf[dk], S1, 0, 0, 0);
        }
        // mask add: reg r=4g+j <-> kv = 4*hi + 8*g + j
        #pragma unroll
        for (int g = 0; g < 4; ++g) {
            S0[4*g+0] = fmaf(mreg[g].x, MSC, S0[4*g+0]);
            S0[4*g+1] = fmaf(mreg[g].y, MSC, S0[4*g+1]);
            S0[4*g+2] = fmaf(mreg[g].z, MSC, S0[4*g+2]);
            S0[4*g+3] = fmaf(mreg[g].w, MSC, S0[4*g+3]);
            S1[4*g+0] = fmaf(mreg[4+g].x, MSC, S1[4*g+0]);
            S1[4*g+1] = fmaf(mreg[4+g].y, MSC, S1[4*g+1]);
            S1[4*g+2] = fmaf(mreg[4+g].z, MSC, S1[4*g+2]);
            S1[4*g+3] = fmaf(mreg[4+g].w, MSC, S1[4*g+3]);
        }

        if (t + 1 < nt) issue_kv(t0 + BKV);   // prefetch next K/V into regs

        // ---- online softmax (log2 domain), row fully lane-local + one xor32 ----
        float tmx[16];
        #pragma unroll
        for (int r = 0; r < 16; ++r) tmx[r] = fmaxf(S0[r], S1[r]);
        #pragma unroll
        for (int w2 = 8; w2 > 0; w2 >>= 1)
            #pragma unroll
            for (int r = 0; r < 8; ++r) if (r < w2) tmx[r] = fmaxf(tmx[r], tmx[r + w2]);
        float pm = fmaxf(tmx[0], __shfl_xor(tmx[0], 32));

        if (__any(pm > m_r + THR)) {          // rare rescale path
            float mnew = fmaxf(m_r, pm);
            float scw = __builtin_amdgcn_exp2f(m_r - mnew);
            if (lane < 32) scb[wave][lane] = scw;
            #pragma unroll
            for (int g = 0; g < 4; ++g) {
                float4 s4 = *(const float4*)&scb[wave][hi * 4 + g * 8];
                acc0[4*g+0] *= s4.x; acc1[4*g+0] *= s4.x;
                acc0[4*g+1] *= s4.y; acc1[4*g+1] *= s4.y;
                acc0[4*g+2] *= s4.z; acc1[4*g+2] *= s4.z;
                acc0[4*g+3] *= s4.w; acc1[4*g+3] *= s4.w;
            }
            l_r *= scw; m_r = mnew;
        }
        float ps = 0.f;
        #pragma unroll
        for (int r = 0; r < 16; ++r) { float p = __builtin_amdgcn_exp2f(S0[r] - m_r); ps += p; S0[r] = p; }
        #pragma unroll
        for (int r = 0; r < 16; ++r) { float p = __builtin_amdgcn_exp2f(S1[r] - m_r); ps += p; S1[r] = p; }
        ps += __shfl_xor(ps, 32);
        l_r += ps;

        // ---- P fragments (in-register, 2 shfl per 16-kv chunk) ----
        bf16x8 pf0 = buildfrag(S0[0], S0[1], S0[2],  S0[3],  S0[4],  S0[5],  S0[6],  S0[7]);
        bf16x8 pf1 = buildfrag(S0[8], S0[9], S0[10], S0[11], S0[12], S0[13], S0[14], S0[15]);
        bf16x8 pf2 = buildfrag(S1[0], S1[1], S1[2],  S1[3],  S1[4],  S1[5],  S1[6],  S1[7]);
        bf16x8 pf3 = buildfrag(S1[8], S1[9], S1[10], S1[11], S1[12], S1[13], S1[14], S1[15]);

        if (t + 1 < nt) issue_mask(t0 + BKV); // prefetch next mask into regs

        // ---- PV ----
        #pragma unroll
        for (int c = 0; c < 4; ++c) {
            bf16x8 pf = (c == 0) ? pf0 : (c == 1) ? pf1 : (c == 2) ? pf2 : pf3;
            bf16x8 vf0 = *(const bf16x8*)&Vt[lq][c * 16 + hi * 8];
            bf16x8 vf1 = *(const bf16x8*)&Vt[32 + lq][c * 16 + hi * 8];
            acc0 = __builtin_amdgcn_mfma_f32_32x32x16_bf16(pf, vf0, acc0, 0, 0, 0);
            acc1 = __builtin_amdgcn_mfma_f32_32x32x16_bf16(pf, vf1, acc1, 0, 0, 0);
        }
    }

    if (SPLIT == 1) {
        if (lane < 32) scb[wave][lane] = 1.0f / l_r;
        #pragma unroll
        for (int g = 0; g < 4; ++g) {
            float4 s4 = *(const float4*)&scb[wave][hi * 4 + g * 8];
            #pragma unroll
            for (int j = 0; j < 4; ++j) {
                int qrow = qbase + hi * 4 + g * 8 + j;
                float sc = (j == 0) ? s4.x : (j == 1) ? s4.y : (j == 2) ? s4.z : s4.w;
                float* op = out + ((size_t)b * NSEQ + qrow) * 128 + kk * 64;
                op[lq]      = acc0[4*g+j] * sc;
                op[32 + lq] = acc1[4*g+j] * sc;
            }
        }
    } else {
        float* pp = part + (size_t)((((b * 2 + kk) * 16 + qt) * SPLIT) + sp) * PSTRIDE;
        #pragma unroll
        for (int g = 0; g < 4; ++g) {
            #pragma unroll
            for (int j = 0; j < 4; ++j) {
                int qloc = wave * 32 + hi * 4 + g * 8 + j;
                pp[qloc * 64 + lq]      = acc0[4*g+j];
                pp[qloc * 64 + 32 + lq] = acc1[4*g+j];
            }
        }
        if (lane < 32) {
            int wl = wave * 32 + lane;
            pp[8192 + wl] = m_r;
            pp[8320 + wl] = l_r;
        }
    }
}

// ---------------- combine partials (+ fused lb loss) ----------------
__global__ __launch_bounds__(256)
void combine_kernel(const float* __restrict__ part, float* __restrict__ out,
                    const float* __restrict__ ws_sm, const int* __restrict__ ws_idx,
                    float* __restrict__ out_lb) {
    const int qt = blockIdx.x, kk = blockIdx.y, b = blockIdx.z;
    const float* base = part + (size_t)(((b * 2 + kk) * 16 + qt) * 4) * PSTRIDE;
    const int row = threadIdx.x >> 1;
    const int half = threadIdx.x & 1;

    float M = -1e30f;
    #pragma unroll
    for (int s = 0; s < 4; ++s) M = fmaxf(M, base[(size_t)s * PSTRIDE + 8192 + row]);

    float L = 0.f;
    float4 o[8];
    #pragma unroll
    for (int j = 0; j < 8; ++j) o[j] = make_float4(0.f, 0.f, 0.f, 0.f);

    #pragma unroll
    for (int s = 0; s < 4; ++s) {
        const float* pb = base + (size_t)s * PSTRIDE;
        float w = __builtin_amdgcn_exp2f(pb[8192 + row] - M);
        L += w * pb[8320 + row];
        const float4* ap = (const float4*)(pb + row * 64 + half * 32);
        #pragma unroll
        for (int j = 0; j < 8; ++j) {
            float4 a = ap[j];
            o[j].x += w * a.x; o[j].y += w * a.y;
            o[j].z += w * a.z; o[j].w += w * a.w;
        }
    }
    float inv = 1.0f / L;
    float* op = out + ((size_t)b * NSEQ + qt * 128 + row) * 128 + kk * 64 + half * 32;
    #pragma unroll
    for (int j = 0; j < 8; ++j) {
        float4 r = make_float4(o[j].x * inv, o[j].y * inv, o[j].z * inv, o[j].w * inv);
        ((float4*)op)[j] = r;
    }
    if (qt == 0 && kk == 0 && b == 0 && threadIdx.x == 0)
        lb_compute(ws_sm, ws_idx, out_lb);
}

extern "C" void kernel_launch(void* const* d_in, const int* in_sizes, int n_in,
                              void* d_out, int out_size, void* d_ws, size_t ws_size,
                              hipStream_t stream) {
    const float* q    = (const float*)d_in[0];
    const float* k    = (const float*)d_in[1];
    const float* v    = (const float*)d_in[2];
    const float* gi   = (const float*)d_in[3];
    const float* mask = (const float*)d_in[4];
    const float* Wg   = (const float*)d_in[5];
    const float* bg   = (const float*)d_in[6];
    float* out = (float*)d_out;
    float* out_lb = out + (size_t)8 * NSEQ * 128;

    const size_t part_bytes = (size_t)1024 * PSTRIDE * 4;               // 34,603,008
    const size_t gateA_bytes = (size_t)8 * 64 * 128 * 4 + 4096;
    const size_t needA = part_bytes + gateA_bytes;
    const size_t needB = 65536 + part_bytes;

    int SL, SPLIT;
    float* ws_part;
    float* wsA;
    if (ws_size >= needA) {
        SL = 64; SPLIT = 4;
        ws_part = (float*)d_ws;
        wsA = (float*)((char*)d_ws + part_bytes);
    } else if (ws_size >= needB) {
        SL = 8; SPLIT = 4;
        wsA = (float*)d_ws;
        ws_part = (float*)((char*)d_ws + 65536);
    } else {
        SL = 8; SPLIT = 1;
        wsA = (float*)d_ws;
        ws_part = (float*)d_ws;
    }
    float* ws_sm = wsA + 8 * SL * 128;
    int*   ws_idx = (int*)(ws_sm + 8 * NH);

    gate_partial<<<8 * SL, 256, 0, stream>>>(gi, wsA, SL);
    gate_final<<<8, 256, 0, stream>>>(wsA, Wg, bg, ws_sm, ws_idx, SL);

    if (SPLIT == 4) {
        dim3 grid(16 * 4, 2, 8);
        attn_kernel<4><<<grid, 256, 0, stream>>>(q, k, v, mask, ws_idx, out, ws_part);
        dim3 cgrid(16, 2, 8);
        combine_kernel<<<cgrid, 256, 0, stream>>>(ws_part, out, ws_sm, ws_idx, out_lb);
    } else {
        lb_kernel<<<1, 64, 0, stream>>>(ws_sm, ws_idx, out_lb);
        dim3 grid(16, 2, 8);
        attn_kernel<1><<<grid, 256, 0, stream>>>(q, k, v, mask, ws_idx, out, ws_part);
    }
}